// Round 3
// baseline (362.949 us; speedup 1.0000x reference)
//
#include <hip/hip_runtime.h>
#include <hip/hip_bf16.h>

// RelativeAttention: out = softmax((QK^T + Sh + Sw)/8) V,  Q/K/V = feature @ W^T + b
// B=2, N=4096, D=512, DK=64.  Memory-bound on streaming Sh+Sw (268 MB).
// R6: producer/consumer wave specialization.
//   R2 post-mortem: bias BW saturates ~3 TB/s; vmcnt retires IN ORDER, so any K/V
//   wait after a bias load force-drains the bias stream -> lookahead hard-capped at
//   1 chunk. Fix: 512-thread blocks, waves 0-3 = consumers (K/V-only vmcnt queue),
//   waves 4-7 = producers (pure bias stream, 12-deep rolling loads, 1 KB contiguous
//   segments = one row's 256-key window per instruction, 8x current burst size).
//   Producers publish pre-scaled bf16 (Sh+Sw)*Cs slots to an LDS ring; acquire/
//   release LDS flags; ring = 2 slots = the whole split (never recycled).

typedef short bf16x8 __attribute__((ext_vector_type(8)));
typedef short bf16x4 __attribute__((ext_vector_type(4)));
typedef float f32x4  __attribute__((ext_vector_type(4)));

#if __has_builtin(__builtin_amdgcn_exp2f)
#define EXP2F(x) __builtin_amdgcn_exp2f(x)
#else
#define EXP2F(x) exp2f(x)
#endif
#if __has_builtin(__builtin_amdgcn_rcpf)
#define RCPF(x) __builtin_amdgcn_rcpf(x)
#else
#define RCPF(x) (1.0f / (x))
#endif

__device__ __forceinline__ f32x4 mfma16(bf16x8 a, bf16x8 b, f32x4 c) {
  return __builtin_amdgcn_mfma_f32_16x16x32_bf16(a, b, c, 0, 0, 0);
}
__device__ __forceinline__ short f2b(float x) {
  __hip_bfloat16 h = __float2bfloat16(x);
  return __builtin_bit_cast(short, h);
}
__device__ __forceinline__ float b2f(short s) {
  return __bfloat162float(__builtin_bit_cast(__hip_bfloat16, s));
}
__device__ __forceinline__ void split_hl(float x, short& h, short& l) {
  __hip_bfloat16 bh = __float2bfloat16(x);
  h = __builtin_bit_cast(short, bh);
  l = f2b(x - __bfloat162float(bh));
}

// ---------------- kernel 1: weight fp32 -> bf16 hi/lo ----------------
__global__ void wcvt_kernel(const float* __restrict__ wq, const float* __restrict__ wk,
                            const float* __restrict__ wv,
                            short* __restrict__ wh, short* __restrict__ wl) {
  int idx = (blockIdx.x * 256 + threadIdx.x) * 4;
  int p = idx >> 15;
  int off = idx & 32767;
  const float* src = (p == 0) ? wq : (p == 1) ? wk : wv;
  f32x4 v = *(const f32x4*)(src + off);
  bf16x4 h, l;
#pragma unroll
  for (int j = 0; j < 4; ++j) { short hh, ll; split_hl(v[j], hh, ll); h[j] = hh; l[j] = ll; }
  *(bf16x4*)(wh + p * 32768 + off) = h;
  *(bf16x4*)(wl + p * 32768 + off) = l;
}

// ---------------- kernel 2: projections, p-split across waves ----------------
// Q is pre-scaled by log2(e)/8 so attn does exp2(qk + bias*Cs) directly.
__global__ __launch_bounds__(256) void proj_kernel(
    const float* __restrict__ feat, const short* __restrict__ wh, const short* __restrict__ wl,
    const float* __restrict__ bq, const float* __restrict__ bk, const float* __restrict__ bv,
    short* __restrict__ Qh, short* __restrict__ Ql,
    short* __restrict__ Kh, short* __restrict__ Kl, short* __restrict__ Vt) {
  const int lane = threadIdx.x & 63, wave = threadIdx.x >> 6;
  const int lq = lane & 15, quad = lane >> 4;
  const int wid = blockIdx.x * 4 + wave;   // 0..1535
  const int p = wid >> 9, rg = wid & 511;
  const int rbase = rg * 16;
  const float Cs = 0.18033688011112042f;   // log2(e)/8

  f32x4 acc[4];
#pragma unroll
  for (int t = 0; t < 4; ++t) acc[t] = (f32x4){0.f, 0.f, 0.f, 0.f};

  const float* frow = feat + (size_t)(rbase + lq) * 512 + quad * 8;
  const int wrow = p * 64;
  for (int ks = 0; ks < 16; ++ks) {
    f32x4 f0 = *(const f32x4*)(frow + ks * 32);
    f32x4 f1 = *(const f32x4*)(frow + ks * 32 + 4);
    bf16x8 fh, fl;
#pragma unroll
    for (int j = 0; j < 4; ++j) {
      short hh, ll;
      split_hl(f0[j], hh, ll); fh[j] = hh; fl[j] = ll;
      split_hl(f1[j], hh, ll); fh[j + 4] = hh; fl[j + 4] = ll;
    }
#pragma unroll
    for (int t = 0; t < 4; ++t) {
      const int wo = (wrow + t * 16 + lq) * 512 + ks * 32 + quad * 8;
      bf16x8 wfh = *(const bf16x8*)(wh + wo);
      bf16x8 wfl = *(const bf16x8*)(wl + wo);
      acc[t] = mfma16(fh, wfh, acc[t]);
      acc[t] = mfma16(fl, wfh, acc[t]);
      acc[t] = mfma16(fh, wfl, acc[t]);
    }
  }
  const int b = rbase >> 12, rloc = rbase & 4095;
  if (p == 0) {
#pragma unroll
    for (int t = 0; t < 4; ++t) {
      const int dk = t * 16 + lq;
      const float bb = bq[dk];
#pragma unroll
      for (int r = 0; r < 4; ++r) {
        const int row = rbase + 4 * quad + r;
        short h, l;
        split_hl((acc[t][r] + bb) * Cs, h, l);
        Qh[row * 64 + dk] = h; Ql[row * 64 + dk] = l;
      }
    }
  } else if (p == 1) {
#pragma unroll
    for (int t = 0; t < 4; ++t) {
      const int dk = t * 16 + lq;
      const float bb = bk[dk];
#pragma unroll
      for (int r = 0; r < 4; ++r) {
        const int row = rbase + 4 * quad + r;
        short h, l;
        split_hl(acc[t][r] + bb, h, l);
        Kh[row * 64 + dk] = h; Kl[row * 64 + dk] = l;
      }
    }
  } else {
#pragma unroll
    for (int t = 0; t < 4; ++t) {
      const int dk = t * 16 + lq;
      const float bb = bv[dk];
      bf16x4 vpack;
#pragma unroll
      for (int r = 0; r < 4; ++r) vpack[r] = f2b(acc[t][r] + bb);
      *(bf16x4*)(Vt + (size_t)(b * 64 + dk) * 4096 + rloc + 4 * quad) = vpack;
    }
  }
}

// ---------------- kernel 3: fused biased attention, producer/consumer ----------------
// grid = B(2) * qtiles(64) * splits(8) = 1024 blocks, 512 threads (8 waves).
// Pair w (w=0..3): consumer wave w + producer wave w+4, rows qt*64 + w*16 .. +16.
// Producer: streams [16 rows x 512 keys] of Sh+Sw in 1 KB contiguous loads (one
//   row's 256-key slot window per instruction), 12 loads in rolling flight
//   (uniform-latency vmcnt queue -> counted waits, never force-drained), converts
//   to bf16 (Sh+Sw)*Cs, fills Ring[w][slot][16][264], sets ready flag (release).
// Consumer: per slot (acquire-spin), 8 chunks of 32 keys: K/V reg loads (L2-hot,
//   the ONLY things in this wave's vmcnt queue), QK, bias from Ring, exp2, PV.
__global__ __launch_bounds__(512, 4) void attn_kernel(
    const float* __restrict__ Sh, const float* __restrict__ Sw,
    const short* __restrict__ Qh, const short* __restrict__ Ql,
    const short* __restrict__ Kh, const short* __restrict__ Vt,
    float* __restrict__ Opart, float* __restrict__ lpart) {
  __shared__ short Ring[4][2][16][264];  // per-pair 2 slots of (Sh+Sw)*Cs bf16 [q16][key256], pad 8
  __shared__ short Plds[4][16][40];      // per-consumer-wave P[q16][key32] bf16
  __shared__ int ready[4][2];
  const int bid = blockIdx.x;
  const int sp = bid & 7, qt = (bid >> 3) & 63, b = bid >> 9;
  const int tid = threadIdx.x;
  const int wave = tid >> 6, lane = tid & 63, lq = lane & 15, quad = lane >> 4;
  const float Cs = 0.18033688011112042f;  // log2(e)/8 (Q already pre-scaled)

  if (wave < 4 && lane < 2) ready[wave][lane] = 0;
  __syncthreads();  // only barrier in the kernel: flag init visibility

  if (wave >= 4) {
    // ================= producer =================
    const int pw = wave - 4;
    const int qbase = qt * 64 + pw * 16;
    const float* shs = Sh + (size_t)(b * 4096 + qbase) * 4096 + sp * 512 + lane * 4;
    const float* sws = Sw + (size_t)(b * 4096 + qbase) * 4096 + sp * 512 + lane * 4;
    short* ring = &Ring[pw][0][0][0];
#pragma unroll
    for (int sl = 0; sl < 2; ++sl) {
      const size_t so = (size_t)sl * 256;
      f32x4 ra[6], rb[6];
#pragma unroll
      for (int r = 0; r < 6; ++r) {
        ra[r] = __builtin_nontemporal_load((const f32x4*)(shs + (size_t)r * 4096 + so));
        rb[r] = __builtin_nontemporal_load((const f32x4*)(sws + (size_t)r * 4096 + so));
      }
#pragma unroll
      for (int r = 0; r < 16; ++r) {
        f32x4 s = (ra[r % 6] + rb[r % 6]) * Cs;
        bf16x4 pk;
#pragma unroll
        for (int j = 0; j < 4; ++j) pk[j] = f2b(s[j]);
        *(bf16x4*)(ring + (sl * 16 + r) * 264 + lane * 4) = pk;
        if (r + 6 < 16) {
          ra[r % 6] = __builtin_nontemporal_load((const f32x4*)(shs + (size_t)(r + 6) * 4096 + so));
          rb[r % 6] = __builtin_nontemporal_load((const f32x4*)(sws + (size_t)(r + 6) * 4096 + so));
        }
      }
      __hip_atomic_store(&ready[pw][sl], 1, __ATOMIC_RELEASE, __HIP_MEMORY_SCOPE_WORKGROUP);
    }
    return;
  }

  // ================= consumer =================
  const int qbase = qt * 64 + wave * 16;
  const int qidx = (b * 4096 + qbase + lq) * 64 + quad * 8;
  const bf16x8 qfh0 = *(const bf16x8*)(Qh + qidx);
  const bf16x8 qfh1 = *(const bf16x8*)(Qh + qidx + 32);
  const bf16x8 qfl0 = *(const bf16x8*)(Ql + qidx);
  const bf16x8 qfl1 = *(const bf16x8*)(Ql + qidx + 32);

  f32x4 accO[4];
#pragma unroll
  for (int u = 0; u < 4; ++u) accO[u] = (f32x4){0.f, 0.f, 0.f, 0.f};
  float lsum = 0.f;
  short* pw_ = &Plds[wave][0][0];
  const short* vbase = Vt + (size_t)b * 64 * 4096;

  for (int sl = 0; sl < 2; ++sl) {
    while (__hip_atomic_load(&ready[wave][sl], __ATOMIC_ACQUIRE, __HIP_MEMORY_SCOPE_WORKGROUP) == 0)
      __builtin_amdgcn_s_sleep(2);
    const short* biasb = &Ring[wave][sl][0][0];
#pragma unroll
    for (int cc = 0; cc < 8; ++cc) {
      const int kb = sp * 512 + sl * 256 + cc * 32;
      bf16x8 kh0[2], kh1[2];
#pragma unroll
      for (int t = 0; t < 2; ++t) {
        const int kidx = (b * 4096 + kb + t * 16 + lq) * 64 + quad * 8;
        kh0[t] = *(const bf16x8*)(Kh + kidx);
        kh1[t] = *(const bf16x8*)(Kh + kidx + 32);
      }
      bf16x8 vf[4];
#pragma unroll
      for (int u = 0; u < 4; ++u)
        vf[u] = *(const bf16x8*)(vbase + (size_t)(u * 16 + lq) * 4096 + kb + quad * 8);

      // QK^T transposed: accS[t][r] = score[key=16t+4quad+r][q=lq] (pre-scaled domain)
      f32x4 accS[2];
#pragma unroll
      for (int t = 0; t < 2; ++t) accS[t] = (f32x4){0.f, 0.f, 0.f, 0.f};
#pragma unroll
      for (int t = 0; t < 2; ++t) {
        accS[t] = mfma16(kh0[t], qfh0, accS[t]);
        accS[t] = mfma16(kh1[t], qfh1, accS[t]);
        accS[t] = mfma16(kh0[t], qfl0, accS[t]);
        accS[t] = mfma16(kh1[t], qfl1, accS[t]);
      }

      // bias from ring, exp2, P write (wave-private P buffer, no barriers)
#pragma unroll
      for (int t = 0; t < 2; ++t) {
        const bf16x4 bb = *(const bf16x4*)(biasb + lq * 264 + cc * 32 + 16 * t + 4 * quad);
        bf16x4 pk;
#pragma unroll
        for (int r = 0; r < 4; ++r) {
          float s = accS[t][r] + b2f(bb[r]);
          float p = EXP2F(s);
          lsum += p;
          pk[r] = f2b(p);
        }
        *(bf16x4*)(pw_ + lq * 40 + 16 * t + 4 * quad) = pk;
      }

      // PV: A = P[q][key0..31] (one bf16x8/lane), B = Vt rows
      const bf16x8 pa = *(const bf16x8*)(pw_ + lq * 40 + quad * 8);
#pragma unroll
      for (int u = 0; u < 4; ++u) accO[u] = mfma16(pa, vf[u], accO[u]);
    }
  }

  // lsum (q=lq) partial over this lane's keys; reduce across quads
  lsum += __shfl_xor(lsum, 16, 64);
  lsum += __shfl_xor(lsum, 32, 64);

  const int orowW = sp * 8192 + b * 4096 + qbase;
  if (quad == 0) lpart[orowW + lq] = lsum;
#pragma unroll
  for (int u = 0; u < 4; ++u)
#pragma unroll
    for (int r = 0; r < 4; ++r)
      Opart[(size_t)(orowW + 4 * quad + r) * 64 + u * 16 + lq] = accO[u][r];
}

// ---------------- kernel 4: combine splits (float4 + fast rcp) ----------------
__global__ void combine_kernel(const float* __restrict__ Opart, const float* __restrict__ lpart,
                               float* __restrict__ out) {
  const int g = blockIdx.x * 256 + threadIdx.x;  // 0..131071 (x4 floats)
  const int row = g >> 4;
  f32x4 o = (f32x4){0.f, 0.f, 0.f, 0.f};
  float l = 0.f;
#pragma unroll
  for (int s = 0; s < 8; ++s) {
    o += __builtin_nontemporal_load((const f32x4*)(Opart + (size_t)s * 524288 + g * 4));
    l += lpart[s * 8192 + row];
  }
  const float rl = RCPF(l);
  *(f32x4*)(out + g * 4) = o * rl;
}

extern "C" void kernel_launch(void* const* d_in, const int* in_sizes, int n_in,
                              void* d_out, int out_size, void* d_ws, size_t ws_size,
                              hipStream_t stream) {
  const float* feature = (const float*)d_in[0];
  const float* Sh = (const float*)d_in[1];
  const float* Sw = (const float*)d_in[2];
  const float* wq = (const float*)d_in[3];
  const float* bq = (const float*)d_in[4];
  const float* wk = (const float*)d_in[5];
  const float* bk = (const float*)d_in[6];
  const float* wv = (const float*)d_in[7];
  const float* bv = (const float*)d_in[8];

  char* ws = (char*)d_ws;
  const size_t MB = 1u << 20;
  short* Qh = (short*)(ws + 0 * MB);            // 1 MB   (8192*64 bf16)
  short* Ql = (short*)(ws + 1 * MB);            // 1 MB
  short* Kh = (short*)(ws + 2 * MB);            // 1 MB
  short* Kl = (short*)(ws + 3 * MB);            // 1 MB (written by proj, unused in attn)
  short* Vt = (short*)(ws + 4 * MB);            // 1 MB   [b][64][4096]
  short* wh = (short*)(ws + 5 * MB);            // 192 KB
  short* wl = (short*)(ws + 5 * MB + 262144);   // 192 KB
  float* lpart = (float*)(ws + 5 * MB + 524288);// 256 KB [8][8192]
  float* Opart = (float*)(ws + 6 * MB);         // 16.78 MB [8][8192][64]

  wcvt_kernel<<<96, 256, 0, stream>>>(wq, wk, wv, wh, wl);
  proj_kernel<<<384, 256, 0, stream>>>(feature, wh, wl, bq, bk, bv, Qh, Ql, Kh, Kl, Vt);
  attn_kernel<<<1024, 512, 0, stream>>>(Sh, Sw, Qh, Ql, Kh, Vt, Opart, lpart);
  combine_kernel<<<512, 256, 0, stream>>>(Opart, lpart, (float*)d_out);
}

// Round 4
// 362.614 us; speedup vs baseline: 1.0009x; 1.0009x over previous
//
#include <hip/hip_runtime.h>
#include <hip/hip_bf16.h>

// RelativeAttention: out = softmax((QK^T + Sh + Sw)/8) V,  Q/K/V = feature @ W^T + b
// B=2, N=4096, D=512, DK=64.  Memory-bound on streaming Sh+Sw (268 MB).
// R7: producer/consumer v2 — few fat DRAM streams.
//   R3 autopsy: 2048 short-run bias streams -> DRAM page thrash, service ~1.5-2.7
//   TB/s no matter the in-flight depth. Fix: ONE producer wave per block (512
//   streams chip-wide), 4 KB sequential runs (2-row groups, Sh then Sw), 16
//   rolling 1KB loads (counted vmcnt, pure bias queue). Producer converts to
//   pre-scaled bf16 and fills 4 per-consumer LDS strips; runs the whole block
//   lifetime (it is the long pole -> no dead time). Consumers = R1 inner loop
//   with pure L2-hot K/V vmcnt queue (bias from LDS) -> no forced drains ever.

typedef short bf16x8 __attribute__((ext_vector_type(8)));
typedef short bf16x4 __attribute__((ext_vector_type(4)));
typedef float f32x4  __attribute__((ext_vector_type(4)));

#if __has_builtin(__builtin_amdgcn_exp2f)
#define EXP2F(x) __builtin_amdgcn_exp2f(x)
#else
#define EXP2F(x) exp2f(x)
#endif
#if __has_builtin(__builtin_amdgcn_rcpf)
#define RCPF(x) __builtin_amdgcn_rcpf(x)
#else
#define RCPF(x) (1.0f / (x))
#endif

__device__ __forceinline__ f32x4 mfma16(bf16x8 a, bf16x8 b, f32x4 c) {
  return __builtin_amdgcn_mfma_f32_16x16x32_bf16(a, b, c, 0, 0, 0);
}
__device__ __forceinline__ short f2b(float x) {
  __hip_bfloat16 h = __float2bfloat16(x);
  return __builtin_bit_cast(short, h);
}
__device__ __forceinline__ float b2f(short s) {
  return __bfloat162float(__builtin_bit_cast(__hip_bfloat16, s));
}
__device__ __forceinline__ void split_hl(float x, short& h, short& l) {
  __hip_bfloat16 bh = __float2bfloat16(x);
  h = __builtin_bit_cast(short, bh);
  l = f2b(x - __bfloat162float(bh));
}

// ---------------- kernel 1: weight fp32 -> bf16 hi/lo ----------------
__global__ void wcvt_kernel(const float* __restrict__ wq, const float* __restrict__ wk,
                            const float* __restrict__ wv,
                            short* __restrict__ wh, short* __restrict__ wl) {
  int idx = (blockIdx.x * 256 + threadIdx.x) * 4;
  int p = idx >> 15;
  int off = idx & 32767;
  const float* src = (p == 0) ? wq : (p == 1) ? wk : wv;
  f32x4 v = *(const f32x4*)(src + off);
  bf16x4 h, l;
#pragma unroll
  for (int j = 0; j < 4; ++j) { short hh, ll; split_hl(v[j], hh, ll); h[j] = hh; l[j] = ll; }
  *(bf16x4*)(wh + p * 32768 + off) = h;
  *(bf16x4*)(wl + p * 32768 + off) = l;
}

// ---------------- kernel 2: projections, p-split across waves ----------------
// Q is pre-scaled by log2(e)/8 so attn does exp2(qk + bias*Cs) directly.
__global__ __launch_bounds__(256) void proj_kernel(
    const float* __restrict__ feat, const short* __restrict__ wh, const short* __restrict__ wl,
    const float* __restrict__ bq, const float* __restrict__ bk, const float* __restrict__ bv,
    short* __restrict__ Qh, short* __restrict__ Ql,
    short* __restrict__ Kh, short* __restrict__ Kl, short* __restrict__ Vt) {
  const int lane = threadIdx.x & 63, wave = threadIdx.x >> 6;
  const int lq = lane & 15, quad = lane >> 4;
  const int wid = blockIdx.x * 4 + wave;   // 0..1535
  const int p = wid >> 9, rg = wid & 511;
  const int rbase = rg * 16;
  const float Cs = 0.18033688011112042f;   // log2(e)/8

  f32x4 acc[4];
#pragma unroll
  for (int t = 0; t < 4; ++t) acc[t] = (f32x4){0.f, 0.f, 0.f, 0.f};

  const float* frow = feat + (size_t)(rbase + lq) * 512 + quad * 8;
  const int wrow = p * 64;
  for (int ks = 0; ks < 16; ++ks) {
    f32x4 f0 = *(const f32x4*)(frow + ks * 32);
    f32x4 f1 = *(const f32x4*)(frow + ks * 32 + 4);
    bf16x8 fh, fl;
#pragma unroll
    for (int j = 0; j < 4; ++j) {
      short hh, ll;
      split_hl(f0[j], hh, ll); fh[j] = hh; fl[j] = ll;
      split_hl(f1[j], hh, ll); fh[j + 4] = hh; fl[j + 4] = ll;
    }
#pragma unroll
    for (int t = 0; t < 4; ++t) {
      const int wo = (wrow + t * 16 + lq) * 512 + ks * 32 + quad * 8;
      bf16x8 wfh = *(const bf16x8*)(wh + wo);
      bf16x8 wfl = *(const bf16x8*)(wl + wo);
      acc[t] = mfma16(fh, wfh, acc[t]);
      acc[t] = mfma16(fl, wfh, acc[t]);
      acc[t] = mfma16(fh, wfl, acc[t]);
    }
  }
  const int b = rbase >> 12, rloc = rbase & 4095;
  if (p == 0) {
#pragma unroll
    for (int t = 0; t < 4; ++t) {
      const int dk = t * 16 + lq;
      const float bb = bq[dk];
#pragma unroll
      for (int r = 0; r < 4; ++r) {
        const int row = rbase + 4 * quad + r;
        short h, l;
        split_hl((acc[t][r] + bb) * Cs, h, l);
        Qh[row * 64 + dk] = h; Ql[row * 64 + dk] = l;
      }
    }
  } else if (p == 1) {
#pragma unroll
    for (int t = 0; t < 4; ++t) {
      const int dk = t * 16 + lq;
      const float bb = bk[dk];
#pragma unroll
      for (int r = 0; r < 4; ++r) {
        const int row = rbase + 4 * quad + r;
        short h, l;
        split_hl(acc[t][r] + bb, h, l);
        Kh[row * 64 + dk] = h; Kl[row * 64 + dk] = l;
      }
    }
  } else {
#pragma unroll
    for (int t = 0; t < 4; ++t) {
      const int dk = t * 16 + lq;
      const float bb = bv[dk];
      bf16x4 vpack;
#pragma unroll
      for (int r = 0; r < 4; ++r) vpack[r] = f2b(acc[t][r] + bb);
      *(bf16x4*)(Vt + (size_t)(b * 64 + dk) * 4096 + rloc + 4 * quad) = vpack;
    }
  }
}

// ---------------- kernel 3: fused biased attention, producer/consumer v2 ----------------
// grid = B(2)*qtiles(64)*splits(8) = 1024 blocks, 320 threads (4 consumers + 1 producer).
// Block covers rows R..R+63 (R = (bid>>3)*64 flattened over b*4096+q), keys sp*512..+512.
// Producer (wave 4): streams the [64 x 512] fp32 strips of Sh and Sw in 2-row groups
//   (4 KB sequential run per matrix per group), double-buffered 16x1KB rolling loads
//   (pure-bias vmcnt queue, counted waits), converts to (Sh+Sw)*Cs bf16, fills
//   Bias[strip s = rows 16s..16s+15], releases ready[s].
// Consumers (waves 0-3): spin once on ready[w], then 16 chunks of 32 keys:
//   K/V reg loads (L2-hot, the ONLY vmem in this wave), QK, bias from LDS, exp2, PV.
__global__ __launch_bounds__(320, 2) void attn_kernel(
    const float* __restrict__ Sh, const float* __restrict__ Sw,
    const short* __restrict__ Qh, const short* __restrict__ Ql,
    const short* __restrict__ Kh, const short* __restrict__ Vt,
    float* __restrict__ Opart, float* __restrict__ lpart) {
  __shared__ short Bias[4][16][520];  // 66560 B: 4 strips of (Sh+Sw)*Cs bf16 [q16][key512]
  __shared__ short Plds[4][16][40];   // 5120 B: per-consumer P[q16][key32]
  __shared__ int ready[4];
  const int bid = blockIdx.x;
  const int sp = bid & 7, qtb = bid >> 3;  // qtb 0..127
  const int R = qtb * 64;                  // flattened row base (b*4096 + q)
  const int b = R >> 12;
  const int tid = threadIdx.x;
  const int wave = tid >> 6, lane = tid & 63;
  const float Cs = 0.18033688011112042f;   // log2(e)/8 (Q already pre-scaled)

  if (wave == 4 && lane < 4) ready[lane] = 0;
  __syncthreads();  // only block-wide barrier: flag init visibility

  if (wave == 4) {
    // ================= producer =================
    const float* shp = Sh + (size_t)R * 4096 + sp * 512;
    const float* swp = Sw + (size_t)R * 4096 + sp * 512;
    const int lo = lane * 4;  // float (and short) offset within a 256-elem half-row

#define LOADG(A, P, G)                                                                     \
    A[0] = __builtin_nontemporal_load((const f32x4*)((P) + (size_t)(2 * (G)) * 4096 + lo));       \
    A[1] = __builtin_nontemporal_load((const f32x4*)((P) + (size_t)(2 * (G)) * 4096 + 256 + lo)); \
    A[2] = __builtin_nontemporal_load((const f32x4*)((P) + (size_t)(2 * (G) + 1) * 4096 + lo));   \
    A[3] = __builtin_nontemporal_load((const f32x4*)((P) + (size_t)(2 * (G) + 1) * 4096 + 256 + lo));

#define STOREG(A, C, G)                                                                    \
    _Pragma("unroll")                                                                      \
    for (int j = 0; j < 4; ++j) {                                                          \
      f32x4 s = (A[j] + C[j]) * Cs;                                                        \
      bf16x4 pk;                                                                           \
      _Pragma("unroll")                                                                    \
      for (int r = 0; r < 4; ++r) pk[r] = f2b(s[r]);                                       \
      *(bf16x4*)(&Bias[(G) >> 3][(2 * (G) + (j >> 1)) & 15][(j & 1) * 256 + lo]) = pk;     \
    }

    f32x4 a0[4], c0[4], a1[4], c1[4];
    LOADG(a0, shp, 0) LOADG(c0, swp, 0)
    LOADG(a1, shp, 1) LOADG(c1, swp, 1)
    for (int g = 0; g < 32; g += 2) {
      STOREG(a0, c0, g)
      if (g + 2 < 32) { LOADG(a0, shp, g + 2) LOADG(c0, swp, g + 2) }
      STOREG(a1, c1, g + 1)
      if (g + 3 < 32) { LOADG(a1, shp, g + 3) LOADG(c1, swp, g + 3) }
      if (((g + 1) & 7) == 7)
        __hip_atomic_store(&ready[(g + 1) >> 3], 1, __ATOMIC_RELEASE, __HIP_MEMORY_SCOPE_WORKGROUP);
    }
#undef LOADG
#undef STOREG
    return;
  }

  // ================= consumer (waves 0..3) =================
  const int lq = lane & 15, quad = lane >> 4;
  const int qbaseF = R + wave * 16;  // flattened row base for this wave
  const int qidx = (qbaseF + lq) * 64 + quad * 8;
  const bf16x8 qfh0 = *(const bf16x8*)(Qh + qidx);
  const bf16x8 qfh1 = *(const bf16x8*)(Qh + qidx + 32);
  const bf16x8 qfl0 = *(const bf16x8*)(Ql + qidx);
  const bf16x8 qfl1 = *(const bf16x8*)(Ql + qidx + 32);

  f32x4 accO[4];
#pragma unroll
  for (int u = 0; u < 4; ++u) accO[u] = (f32x4){0.f, 0.f, 0.f, 0.f};
  float lsum = 0.f;
  short* pw_ = &Plds[wave][0][0];
  const short* bw = &Bias[wave][0][0];
  const short* vbase = Vt + (size_t)b * 64 * 4096;

  while (__hip_atomic_load(&ready[wave], __ATOMIC_ACQUIRE, __HIP_MEMORY_SCOPE_WORKGROUP) == 0)
    __builtin_amdgcn_s_sleep(4);

#pragma unroll 2
  for (int it = 0; it < 16; ++it) {
    const int kb = sp * 512 + it * 32;
    bf16x8 kh0[2], kh1[2];
#pragma unroll
    for (int t = 0; t < 2; ++t) {
      const int kidx = (b * 4096 + kb + t * 16 + lq) * 64 + quad * 8;
      kh0[t] = *(const bf16x8*)(Kh + kidx);
      kh1[t] = *(const bf16x8*)(Kh + kidx + 32);
    }
    bf16x8 vf[4];
#pragma unroll
    for (int u = 0; u < 4; ++u)
      vf[u] = *(const bf16x8*)(vbase + (size_t)(u * 16 + lq) * 4096 + kb + quad * 8);

    // QK^T transposed: accS[t][r] = score[key=16t+4quad+r][q=lq] (pre-scaled domain)
    f32x4 accS[2];
#pragma unroll
    for (int t = 0; t < 2; ++t) accS[t] = (f32x4){0.f, 0.f, 0.f, 0.f};
#pragma unroll
    for (int t = 0; t < 2; ++t) {
      accS[t] = mfma16(kh0[t], qfh0, accS[t]);
      accS[t] = mfma16(kh1[t], qfh1, accS[t]);
      accS[t] = mfma16(kh0[t], qfl0, accS[t]);
      accS[t] = mfma16(kh1[t], qfl1, accS[t]);
    }

    // bias from LDS strip, exp2, P write (wave-private, no barriers)
#pragma unroll
    for (int t = 0; t < 2; ++t) {
      const bf16x4 bb = *(const bf16x4*)(bw + lq * 520 + it * 32 + 16 * t + 4 * quad);
      bf16x4 pk;
#pragma unroll
      for (int r = 0; r < 4; ++r) {
        float s = accS[t][r] + b2f(bb[r]);
        float p = EXP2F(s);
        lsum += p;
        pk[r] = f2b(p);
      }
      *(bf16x4*)(pw_ + lq * 40 + 16 * t + 4 * quad) = pk;
    }

    // PV: A = P[q][key0..31] (one bf16x8/lane), B = Vt rows
    const bf16x8 pa = *(const bf16x8*)(pw_ + lq * 40 + quad * 8);
#pragma unroll
    for (int u = 0; u < 4; ++u) accO[u] = mfma16(pa, vf[u], accO[u]);
  }

  // lsum (q=lq) partial over this lane's keys; reduce across quads
  lsum += __shfl_xor(lsum, 16, 64);
  lsum += __shfl_xor(lsum, 32, 64);

  const int orowW = sp * 8192 + qbaseF;
  if (quad == 0) lpart[orowW + lq] = lsum;
#pragma unroll
  for (int u = 0; u < 4; ++u)
#pragma unroll
    for (int r = 0; r < 4; ++r)
      Opart[(size_t)(orowW + 4 * quad + r) * 64 + u * 16 + lq] = accO[u][r];
}

// ---------------- kernel 4: combine splits (float4 + fast rcp) ----------------
__global__ void combine_kernel(const float* __restrict__ Opart, const float* __restrict__ lpart,
                               float* __restrict__ out) {
  const int g = blockIdx.x * 256 + threadIdx.x;  // 0..131071 (x4 floats)
  const int row = g >> 4;
  f32x4 o = (f32x4){0.f, 0.f, 0.f, 0.f};
  float l = 0.f;
#pragma unroll
  for (int s = 0; s < 8; ++s) {
    o += __builtin_nontemporal_load((const f32x4*)(Opart + (size_t)s * 524288 + g * 4));
    l += lpart[s * 8192 + row];
  }
  const float rl = RCPF(l);
  *(f32x4*)(out + g * 4) = o * rl;
}

extern "C" void kernel_launch(void* const* d_in, const int* in_sizes, int n_in,
                              void* d_out, int out_size, void* d_ws, size_t ws_size,
                              hipStream_t stream) {
  const float* feature = (const float*)d_in[0];
  const float* Sh = (const float*)d_in[1];
  const float* Sw = (const float*)d_in[2];
  const float* wq = (const float*)d_in[3];
  const float* bq = (const float*)d_in[4];
  const float* wk = (const float*)d_in[5];
  const float* bk = (const float*)d_in[6];
  const float* wv = (const float*)d_in[7];
  const float* bv = (const float*)d_in[8];

  char* ws = (char*)d_ws;
  const size_t MB = 1u << 20;
  short* Qh = (short*)(ws + 0 * MB);            // 1 MB   (8192*64 bf16)
  short* Ql = (short*)(ws + 1 * MB);            // 1 MB
  short* Kh = (short*)(ws + 2 * MB);            // 1 MB
  short* Kl = (short*)(ws + 3 * MB);            // 1 MB (written by proj, unused in attn)
  short* Vt = (short*)(ws + 4 * MB);            // 1 MB   [b][64][4096]
  short* wh = (short*)(ws + 5 * MB);            // 192 KB
  short* wl = (short*)(ws + 5 * MB + 262144);   // 192 KB
  float* lpart = (float*)(ws + 5 * MB + 524288);// 256 KB [8][8192]
  float* Opart = (float*)(ws + 6 * MB);         // 16.78 MB [8][8192][64]

  wcvt_kernel<<<96, 256, 0, stream>>>(wq, wk, wv, wh, wl);
  proj_kernel<<<384, 256, 0, stream>>>(feature, wh, wl, bq, bk, bv, Qh, Ql, Kh, Kl, Vt);
  attn_kernel<<<1024, 320, 0, stream>>>(Sh, Sw, Qh, Ql, Kh, Vt, Opart, lpart);
  combine_kernel<<<512, 256, 0, stream>>>(Opart, lpart, (float*)d_out);
}